// Round 11
// baseline (387.312 us; speedup 1.0000x reference)
//
#include <hip/hip_runtime.h>
#include <cstdint>
#include <cstddef>

#define B_ 4
#define C_ 256
#define N_ 4096

typedef __attribute__((ext_vector_type(8))) short s8v;    // 8 bf16 (4 VGPRs) MFMA A/B frag
typedef __attribute__((ext_vector_type(4))) float f4v;    // 16x16 MFMA C/D frag
typedef __attribute__((ext_vector_type(16))) float f16v;  // 32x32 MFMA C/D frag
typedef long long i64f;                                   // 8 fp8 (2 VGPRs) MFMA A/B frag

#if defined(__has_builtin)
#if __has_builtin(__builtin_amdgcn_exp2f)
#define EXP2(x) __builtin_amdgcn_exp2f(x)
#endif
#endif
#ifndef EXP2
#define EXP2(x) exp2f(x)
#endif

// scheduling fence: no instruction may be reordered across (pins prefetch issue)
#define SCHED_FENCE() __builtin_amdgcn_sched_barrier(0)

__device__ __forceinline__ unsigned short f2bf(float f) {
  unsigned int u = __builtin_bit_cast(unsigned int, f);
  return (unsigned short)((u + 0x7FFFu + ((u >> 16) & 1u)) >> 16);  // RNE
}

__device__ __forceinline__ float bf2f(unsigned short u) {
  return __builtin_bit_cast(float, (unsigned)u << 16);
}

__device__ __forceinline__ f16v zf16() {
  f16v z;
#pragma unroll
  for (int i = 0; i < 16; ++i) z[i] = 0.f;
  return z;
}

// Layouts:
//  16x16 B-frag blocked bf16 (aS LDS tile, 32 rows): flat = ((n>>4)*32 + (c>>3))*128 + (n&15)*8 + (c&7)
//  qB bf16 (32x32 B-frag): flat = (((b*128 + r32)*16 + cs)*64 + l)*8 + e
//      holds q[c = cs*16 + (l>>5)*8 + e][n = r32*32 + (l&31)]
//  kB bf16 (32x32 A-frag): flat = (((b*128 + kg)*16 + cs)*64 + l)*8 + e
//  vB FP8 e4m3 (BYTE units): byte = (((b*8 + cg)*256 + ks)*64 + l)*8 + e
//  P LDS fp8 (32 rows): byte = k8*256 + n31*8 + klow   (k8 = key>>3, klow = key&7)

// ---------------- K1: BatchNorm statistics ----------------
__global__ __launch_bounds__(256) void bn_stats(const float* __restrict__ x,
                                                float* __restrict__ mean,
                                                float* __restrict__ rstd) {
  int c = blockIdx.x, t = threadIdx.x;
  float s = 0.f, s2 = 0.f;
  for (int b = 0; b < B_; ++b) {
    const float* p = x + ((size_t)b * C_ + c) * N_;
    for (int n = t; n < N_; n += 256) { float v = p[n]; s += v; s2 += v * v; }
  }
  __shared__ float rs[256], rs2[256];
  rs[t] = s; rs2[t] = s2; __syncthreads();
  for (int off = 128; off > 0; off >>= 1) {
    if (t < off) { rs[t] += rs[t + off]; rs2[t] += rs2[t + off]; }
    __syncthreads();
  }
  if (t == 0) {
    float m = rs[0] * (1.f / 16384.f);
    float v = rs2[0] * (1.f / 16384.f) - m * m;
    mean[c] = m; rstd[c] = rsqrtf(v + 1e-5f);
  }
}

// ---------------- K2: fold BN (and C^-0.5 * log2e into q path) into weights ----------------
__global__ __launch_bounds__(256) void prep(
    const float* __restrict__ wq, const float* __restrict__ bq,
    const float* __restrict__ wk, const float* __restrict__ bk,
    const float* __restrict__ wv, const float* __restrict__ bv,
    const float* __restrict__ wp,
    const float* __restrict__ gamma, const float* __restrict__ beta,
    const float* __restrict__ mean, const float* __restrict__ rstd,
    unsigned short* __restrict__ wqb, unsigned short* __restrict__ wkb,
    unsigned short* __restrict__ wvb, unsigned short* __restrict__ wpb,
    float* __restrict__ beq, float* __restrict__ bek, float* __restrict__ bev) {
  const float QSC = 0.0625f * 1.4426950408889634f;   // C^-0.5 * log2(e)
  int o = blockIdx.x, c = threadIdx.x;
  float a = gamma[c] * rstd[c];
  float d = beta[c] - mean[c] * a;
  float wqv = wq[o * C_ + c], wkv = wk[o * C_ + c], wvv = wv[o * C_ + c];
  wqb[o * C_ + c] = f2bf(wqv * a * QSC);
  wkb[o * C_ + c] = f2bf(wkv * a);
  wvb[o * C_ + c] = f2bf(wvv * a);
  wpb[o * C_ + c] = f2bf(wp[o * C_ + c]);
  __shared__ float r0[256], r1[256], r2[256];
  r0[c] = wqv * d; r1[c] = wkv * d; r2[c] = wvv * d; __syncthreads();
  for (int off = 128; off > 0; off >>= 1) {
    if (c < off) { r0[c] += r0[c + off]; r1[c] += r1[c + off]; r2[c] += r2[c + off]; }
    __syncthreads();
  }
  if (c == 0) {
    beq[o] = (bq[o] + r0[0]) * QSC;
    bek[o] = bk[o] + r1[0];
    bev[o] = bv[o] + r2[0];
  }
}

// ---------------- K3: fused x-convert + QKV GEMM; q/k bf16 frags, v FP8 frags ----------------
__global__ __launch_bounds__(256) void qkv(
    const float* __restrict__ x,
    const unsigned short* __restrict__ wqb, const unsigned short* __restrict__ wkb,
    const unsigned short* __restrict__ wvb,
    const float* __restrict__ beq, const float* __restrict__ bek,
    const float* __restrict__ bev,
    unsigned short* __restrict__ qB, unsigned short* __restrict__ kB,
    unsigned char* __restrict__ vB) {
  int b = blockIdx.z, oblk = blockIdx.y, n0 = blockIdx.x * 64;
  int tid = threadIdx.x, w = tid >> 6, l = tid & 63, quad = l >> 4, lq = l & 15;
  int orow = oblk * 64 + w * 16 + lq;

  __shared__ unsigned short XF[16384];   // 32 KB x tile in 16x16 B-frag layout
  __shared__ unsigned short Ls[64][72];  // staging / repack buffer

  // ---- stage x -> XF (4 c-quarters, xt's transpose pattern) ----
  {
    int cw = tid >> 6, nl = tid & 63;
    for (int cq = 0; cq < 4; ++cq) {
#pragma unroll
      for (int rr = 0; rr < 16; ++rr) {
        int c = cq * 64 + cw * 16 + rr;
        Ls[nl][cw * 16 + rr] = f2bf(x[((size_t)b * C_ + c) * N_ + n0 + nl]);
      }
      __syncthreads();
      int n_ = tid >> 2, cs = (tid & 3) * 16;
      s8v v0 = *(const s8v*)(&Ls[n_][cs]);
      s8v v1 = *(const s8v*)(&Ls[n_][cs + 8]);
      int fr = ((n_ >> 4) * 32 + ((cq * 64 + cs) >> 3)) * 128 + (n_ & 15) * 8;
      *(s8v*)(XF + fr) = v0;
      *(s8v*)(XF + fr + 128) = v1;
      __syncthreads();
    }
  }

  f4v aq[4], ak[4], av[4];
#pragma unroll
  for (int nt = 0; nt < 4; ++nt) {
    aq[nt] = (f4v){0.f, 0.f, 0.f, 0.f};
    ak[nt] = (f4v){0.f, 0.f, 0.f, 0.f};
    av[nt] = (f4v){0.f, 0.f, 0.f, 0.f};
  }

#pragma unroll
  for (int kk = 0; kk < 8; ++kk) {
    s8v afq = *(const s8v*)(wqb + (size_t)orow * C_ + kk * 32 + quad * 8);
    s8v afk = *(const s8v*)(wkb + (size_t)orow * C_ + kk * 32 + quad * 8);
    s8v afv = *(const s8v*)(wvb + (size_t)orow * C_ + kk * 32 + quad * 8);
#pragma unroll
    for (int nt = 0; nt < 4; ++nt) {
      s8v bf = *(const s8v*)(XF + (nt * 32 + kk * 4 + quad) * 128 + lq * 8);
      aq[nt] = __builtin_amdgcn_mfma_f32_16x16x32_bf16(afq, bf, aq[nt], 0, 0, 0);
      ak[nt] = __builtin_amdgcn_mfma_f32_16x16x32_bf16(afk, bf, ak[nt], 0, 0, 0);
      av[nt] = __builtin_amdgcn_mfma_f32_16x16x32_bf16(afv, bf, av[nt], 0, 0, 0);
    }
  }

  int obase = oblk * 64;

  // pass 1: q -> qB ; pass 2: k -> kB   (stage [n][c]; read out in 32x32-frag order)
  for (int pass = 0; pass < 2; ++pass) {
    const f4v* acc = (pass == 0) ? aq : ak;
    const float* BE = (pass == 0) ? beq : bek;
    int ob4 = obase + w * 16 + quad * 4;
    float b0 = BE[ob4], b1 = BE[ob4 + 1], b2 = BE[ob4 + 2], b3 = BE[ob4 + 3];
    __syncthreads();
#pragma unroll
    for (int nt = 0; nt < 4; ++nt) {
      unsigned lo = (unsigned)f2bf(acc[nt][0] + b0) | ((unsigned)f2bf(acc[nt][1] + b1) << 16);
      unsigned hi = (unsigned)f2bf(acc[nt][2] + b2) | ((unsigned)f2bf(acc[nt][3] + b3) << 16);
      uint2 pr; pr.x = lo; pr.y = hi;
      *(uint2*)(&Ls[nt * 16 + lq][w * 16 + quad * 4]) = pr;
    }
    __syncthreads();
    {
      unsigned short* dp = (pass == 0) ? qB : kB;
#pragma unroll
      for (int ii = 0; ii < 2; ++ii) {
        int i = tid + ii * 256;
        int g = i >> 8, cs = (i >> 6) & 3, ll = i & 63;
        s8v vv = *(const s8v*)(&Ls[g * 32 + (ll & 31)][cs * 16 + ((ll >> 5) << 3)]);
        // both q and k use the 32-row-group frag layout: (((b*128 + n32)*16 + cs)*512 + ll*8
        size_t dst = (((size_t)b * 128 + (n0 >> 5) + g) * 16 + (obase >> 4) + cs) * 512 + (size_t)ll * 8;
        *(s8v*)(dp + dst) = vv;
      }
    }
  }
  __syncthreads();

  // pass 3: v (stage [c][n] bf16; read out in 32x32 A-frag order, CONVERT TO FP8 e4m3)
#pragma unroll
  for (int nt = 0; nt < 4; ++nt)
#pragma unroll
    for (int r = 0; r < 4; ++r) {
      int o_ = obase + w * 16 + quad * 4 + r;
      Ls[w * 16 + quad * 4 + r][nt * 16 + lq] = f2bf(av[nt][r] + bev[o_]);
    }
  __syncthreads();
  {
#pragma unroll
    for (int ii = 0; ii < 2; ++ii) {
      int i = tid + ii * 256;
      int g = i >> 8, ks = (i >> 6) & 3, ll = i & 63;
      s8v vv = *(const s8v*)(&Ls[g * 32 + (ll & 31)][ks * 16 + ((ll >> 5) << 3)]);
      unsigned w0 = (unsigned)__builtin_amdgcn_cvt_pk_fp8_f32(
          bf2f((unsigned short)vv[0]), bf2f((unsigned short)vv[1]), 0, false);
      w0 = (unsigned)__builtin_amdgcn_cvt_pk_fp8_f32(
          bf2f((unsigned short)vv[2]), bf2f((unsigned short)vv[3]), (int)w0, true);
      unsigned w1 = (unsigned)__builtin_amdgcn_cvt_pk_fp8_f32(
          bf2f((unsigned short)vv[4]), bf2f((unsigned short)vv[5]), 0, false);
      w1 = (unsigned)__builtin_amdgcn_cvt_pk_fp8_f32(
          bf2f((unsigned short)vv[6]), bf2f((unsigned short)vv[7]), (int)w1, true);
      uint2 pr; pr.x = w0; pr.y = w1;
      size_t dst = ((((size_t)b * 8 + (obase >> 5) + g) * 256 + (n0 >> 4) + ks) * 64 + ll) * 8;
      *(uint2*)(vB + dst) = pr;
    }
  }
}

// ---------------- K4: FMHA v8 — 32 q-rows/block, 512 blocks, 2 blocks/CU (4 waves/SIMD) ----------------
// r10 diagnosis: per-chunk time (~10.8k cyc) invariant to LDS bytes/interleave/
// fences -> bottleneck is the serialized critical path with only 2 waves/SIMD
// (grid 256 = 1 block/CU all session). Fix: halve the q-tile (32 rows), double
// the grid (512 blocks) -> 2 INDEPENDENT blocks per CU. When one block stalls
// at a barrier/vmcnt the other's waves issue (m114 overlap). Per wave: 32 keys
// (S: 16 MFMA bf16) + 32 channels (PV: 16 MFMA fp8). LDS 34 KB (Qs 16K aliased
// as proj tile + 2x8K fp8 P). Live regs ~118 (vf issued AFTER S to cut peak);
// __launch_bounds__(512,4) forces the 128 cap for 4 waves/SIMD.
__global__ __launch_bounds__(512, 4) void attn(
    const unsigned short* __restrict__ qB, const unsigned short* __restrict__ kB,
    const unsigned char* __restrict__ vB,
    const unsigned short* __restrict__ wpb, const float* __restrict__ bp,
    const float* __restrict__ x, float* __restrict__ out) {
  int id = blockIdx.x;                       // 512 blocks; id&7 = XCD (2 XCDs per batch)
  int b = (id & 7) >> 1;
  int r32 = ((id >> 3) << 1) | (id & 1);     // 32-row tile index within batch [0,128)
  int i0 = r32 << 5;
  int tid = threadIdx.x, w = tid >> 6, l = tid & 63;
  int lh = l >> 5, l31 = l & 31;

  __shared__ unsigned short Qs[8192];        // 16 KB q-tile; REUSED as proj-input tile
  __shared__ unsigned char Ps[2][8192];      // 2 x 8 KB P tiles (fp8)
  __shared__ float Lw[8][32];

  // stage q-tile (contiguous 16 KB = 1024 s8v fragments in qB)
  {
    const s8v* g = (const s8v*)(qB + (((size_t)b * 128 + r32) * 16) * 512);
    s8v* sq = (s8v*)Qs;
    sq[tid] = g[tid];
    sq[tid + 512] = g[tid + 512];
  }

  // K: wave w owns key32-group w of each chunk; advance 8 groups = 65536 elems/chunk
  const unsigned short* kp = kB + (((size_t)b * 128 + w) * 16) * 512 + (size_t)l * 8;
  // V (fp8, BYTE addressing): wave w owns channel-group w; frag ks at +ks*512 B
  const unsigned char* vp = vB + (((size_t)b * 8 + w) * 256) * 512 + (size_t)l * 8;
  const unsigned short* Qp = Qs + (size_t)l * 8;   // + cs*512

  // prologue: kf for chunk 0
  s8v kf[16];
#pragma unroll
  for (int cs = 0; cs < 16; ++cs) kf[cs] = *(const s8v*)(kp + cs * 512);
  SCHED_FENCE();

  __syncthreads();  // Qs visible

  f16v O0 = zf16();   // channels w*32+chl, rows i0+l31
  float ls0 = 0.f;

  for (int t = 0; t < 16; ++t) {
    // ---- S phase: this wave's 32 keys x 32 rows (bf16 MFMA) ----
    f16v S0 = zf16();
    __builtin_amdgcn_s_setprio(1);
#pragma unroll
    for (int cs = 0; cs < 16; ++cs) {
      s8v q0 = *(const s8v*)(Qp + cs * 512);
      S0 = __builtin_amdgcn_mfma_f32_32x32x16_bf16(kf[cs], q0, S0, 0, 0, 0);
    }
    __builtin_amdgcn_s_setprio(0);
    SCHED_FENCE();
    // ---- vf prefetch for THIS chunk (fp8, 32 VGPR); latency covered by exp+barrier ----
    i64f vf[16];
#pragma unroll
    for (int ks = 0; ks < 16; ++ks) vf[ks] = *(const i64f*)(vp + ks * 512);
    vp += 8192;
    SCHED_FENCE();
    // ---- exp2 + fp8 pack + P write. key = w*32 + 8j + 4lh + (0..3), row = l31 ----
    unsigned char* Pw = Ps[t & 1] + w * 1024 + l31 * 8 + lh * 4;
#pragma unroll
    for (int j = 0; j < 4; ++j) {
      float a0 = EXP2(S0[4 * j + 0]), a1 = EXP2(S0[4 * j + 1]);
      float a2 = EXP2(S0[4 * j + 2]), a3 = EXP2(S0[4 * j + 3]);
      ls0 += (a0 + a1) + (a2 + a3);
      unsigned p0 = (unsigned)__builtin_amdgcn_cvt_pk_fp8_f32(a0, a1, 0, false);
      p0 = (unsigned)__builtin_amdgcn_cvt_pk_fp8_f32(a2, a3, (int)p0, true);
      *(unsigned*)(Pw + j * 256) = p0;
    }
    __syncthreads();   // P visible
    // ---- kf prefetch for NEXT chunk (lands during PV; t=15 read is benign OOB) ----
    kp += 65536;
#pragma unroll
    for (int cs = 0; cs < 16; ++cs) kf[cs] = *(const s8v*)(kp + cs * 512);
    SCHED_FENCE();
    // ---- PV phase: fp8 MFMA; this wave's 32 channels, all 256 keys ----
    const unsigned char* Pr = Ps[t & 1] + (size_t)lh * 256 + l31 * 8;
    __builtin_amdgcn_s_setprio(1);
#pragma unroll
    for (int ks = 0; ks < 16; ++ks) {
      i64f p0 = *(const i64f*)(Pr + ks * 512);
      O0 = __builtin_amdgcn_mfma_f32_32x32x16_fp8_fp8(vf[ks], p0, O0, 0, 0, 0);
    }
    __builtin_amdgcn_s_setprio(0);
  }

  // ---- wp A-frag prefetch (kf/vf dead now; lands under the reductions) ----
  s8v wf[16];
#pragma unroll
  for (int cs = 0; cs < 16; ++cs)
    wf[cs] = *(const s8v*)(wpb + (size_t)(w * 32 + l31) * 256 + cs * 16 + lh * 8);
  SCHED_FENCE();

  // lsum: lane holds the sums for row l31 over its 16 keys/chunk; l^32 has the rest
  ls0 += __shfl_xor(ls0, 32);
  if (l < 32) Lw[w][l] = ls0;
  __syncthreads();
  float s0 = 0.f;
#pragma unroll
  for (int ww = 0; ww < 8; ++ww) s0 += Lw[ww][l31];
  float rl0 = 1.f / s0;

  // ---- normalize + write attn-out tile to LDS (aliases Qs; 16x16 B-frag, 32 rows) ----
  unsigned short* aS = Qs;
#pragma unroll
  for (int jj = 0; jj < 4; ++jj) {
    ushort4 pk;
    pk.x = f2bf(O0[4 * jj + 0] * rl0); pk.y = f2bf(O0[4 * jj + 1] * rl0);
    pk.z = f2bf(O0[4 * jj + 2] * rl0); pk.w = f2bf(O0[4 * jj + 3] * rl0);
    int f0 = ((l31 >> 4) * 32 + w * 4 + jj) * 128 + (l31 & 15) * 8 + lh * 4;
    *(ushort4*)(aS + f0) = pk;
  }
  __syncthreads();   // aS visible

  // ---- projection GEMM: out[o][n] = sum_c wp[o][c] * a[c][n], n = i0 + l31 ----
  f16v OP0 = zf16();
#pragma unroll
  for (int cs = 0; cs < 16; ++cs) {
    s8v pa0 = *(const s8v*)(aS + ((l31 >> 4) * 32 + cs * 2 + lh) * 128 + (l31 & 15) * 8);
    OP0 = __builtin_amdgcn_mfma_f32_32x32x16_bf16(wf[cs], pa0, OP0, 0, 0, 0);
  }

  // ---- epilogue: out = x + proj + bp ----
#pragma unroll
  for (int r = 0; r < 16; ++r) {
    int o_ = w * 32 + (r & 3) + 8 * (r >> 2) + 4 * lh;
    size_t ix = ((size_t)b * C_ + o_) * N_ + i0 + l31;
    out[ix] = x[ix] + OP0[r] + bp[o_];
  }
}

extern "C" void kernel_launch(void* const* d_in, const int* in_sizes, int n_in,
                              void* d_out, int out_size, void* d_ws, size_t ws_size,
                              hipStream_t stream) {
  const float* x     = (const float*)d_in[0];
  const float* gamma = (const float*)d_in[1];
  const float* beta  = (const float*)d_in[2];
  const float* wq    = (const float*)d_in[3];
  const float* bq    = (const float*)d_in[4];
  const float* wk    = (const float*)d_in[5];
  const float* bk    = (const float*)d_in[6];
  const float* wv    = (const float*)d_in[7];
  const float* bv    = (const float*)d_in[8];
  const float* wp    = (const float*)d_in[9];
  const float* bp    = (const float*)d_in[10];
  float* out = (float*)d_out;

  char* ws = (char*)d_ws;
  float* mean = (float*)ws; ws += 1024;
  float* rstd = (float*)ws; ws += 1024;
  float* beq  = (float*)ws; ws += 1024;
  float* bek  = (float*)ws; ws += 1024;
  float* bev  = (float*)ws; ws += 1024;
  unsigned short* wqb = (unsigned short*)ws; ws += C_ * C_ * 2;
  unsigned short* wkb = (unsigned short*)ws; ws += C_ * C_ * 2;
  unsigned short* wvb = (unsigned short*)ws; ws += C_ * C_ * 2;
  unsigned short* wpb = (unsigned short*)ws; ws += C_ * C_ * 2;
  unsigned short* qB  = (unsigned short*)ws; ws += (size_t)B_ * N_ * C_ * 2;
  unsigned short* kB  = (unsigned short*)ws; ws += (size_t)B_ * N_ * C_ * 2;
  unsigned char*  vB  = (unsigned char*)ws;  ws += (size_t)B_ * N_ * C_ * 2;  // fp8 uses half; slack absorbs OOB prefetch

  hipLaunchKernelGGL(bn_stats, dim3(C_), dim3(256), 0, stream, x, mean, rstd);
  hipLaunchKernelGGL(prep, dim3(C_), dim3(256), 0, stream,
                     wq, bq, wk, bk, wv, bv, wp, gamma, beta, mean, rstd,
                     wqb, wkb, wvb, wpb, beq, bek, bev);
  hipLaunchKernelGGL(qkv, dim3(N_ / 64, 4, B_), dim3(256), 0, stream,
                     x, wqb, wkb, wvb, beq, bek, bev, qB, kB, vB);
  hipLaunchKernelGGL(attn, dim3(512), dim3(512), 0, stream,
                     qB, kB, vB, wpb, bp, x, out);
}

// Round 12
// 214.504 us; speedup vs baseline: 1.8056x; 1.8056x over previous
//
#include <hip/hip_runtime.h>
#include <cstdint>
#include <cstddef>

#define B_ 4
#define C_ 256
#define N_ 4096

typedef __attribute__((ext_vector_type(8))) short s8v;    // 8 bf16 (4 VGPRs) MFMA A/B frag
typedef __attribute__((ext_vector_type(4))) float f4v;    // 16x16 MFMA C/D frag
typedef __attribute__((ext_vector_type(16))) float f16v;  // 32x32 MFMA C/D frag
typedef long long i64f;                                   // 8 fp8 (2 VGPRs) MFMA A/B frag

#if defined(__has_builtin)
#if __has_builtin(__builtin_amdgcn_exp2f)
#define EXP2(x) __builtin_amdgcn_exp2f(x)
#endif
#endif
#ifndef EXP2
#define EXP2(x) exp2f(x)
#endif

// scheduling fence: no instruction may be reordered across (pins prefetch issue)
#define SCHED_FENCE() __builtin_amdgcn_sched_barrier(0)

__device__ __forceinline__ unsigned short f2bf(float f) {
  unsigned int u = __builtin_bit_cast(unsigned int, f);
  return (unsigned short)((u + 0x7FFFu + ((u >> 16) & 1u)) >> 16);  // RNE
}

__device__ __forceinline__ float bf2f(unsigned short u) {
  return __builtin_bit_cast(float, (unsigned)u << 16);
}

__device__ __forceinline__ f16v zf16() {
  f16v z;
#pragma unroll
  for (int i = 0; i < 16; ++i) z[i] = 0.f;
  return z;
}

// Layouts:
//  16x16 B-frag blocked bf16 (aS LDS tile, 32 rows): flat = ((n>>4)*32 + (c>>3))*128 + (n&15)*8 + (c&7)
//  qB bf16 (32x32 B-frag): flat = (((b*128 + r32)*16 + cs)*64 + l)*8 + e
//      holds q[c = cs*16 + (l>>5)*8 + e][n = r32*32 + (l&31)]
//  kB bf16 (32x32 A-frag): flat = (((b*128 + kg)*16 + cs)*64 + l)*8 + e
//  vB FP8 e4m3 (BYTE units): byte = (((b*8 + cg)*256 + ks)*64 + l)*8 + e
//  P LDS fp8 (32 rows): byte = k8*256 + n31*8 + klow   (k8 = key>>3, klow = key&7)

// ---------------- K1: BatchNorm statistics ----------------
__global__ __launch_bounds__(256) void bn_stats(const float* __restrict__ x,
                                                float* __restrict__ mean,
                                                float* __restrict__ rstd) {
  int c = blockIdx.x, t = threadIdx.x;
  float s = 0.f, s2 = 0.f;
  for (int b = 0; b < B_; ++b) {
    const float* p = x + ((size_t)b * C_ + c) * N_;
    for (int n = t; n < N_; n += 256) { float v = p[n]; s += v; s2 += v * v; }
  }
  __shared__ float rs[256], rs2[256];
  rs[t] = s; rs2[t] = s2; __syncthreads();
  for (int off = 128; off > 0; off >>= 1) {
    if (t < off) { rs[t] += rs[t + off]; rs2[t] += rs2[t + off]; }
    __syncthreads();
  }
  if (t == 0) {
    float m = rs[0] * (1.f / 16384.f);
    float v = rs2[0] * (1.f / 16384.f) - m * m;
    mean[c] = m; rstd[c] = rsqrtf(v + 1e-5f);
  }
}

// ---------------- K2: fold BN (and C^-0.5 * log2e into q path) into weights ----------------
__global__ __launch_bounds__(256) void prep(
    const float* __restrict__ wq, const float* __restrict__ bq,
    const float* __restrict__ wk, const float* __restrict__ bk,
    const float* __restrict__ wv, const float* __restrict__ bv,
    const float* __restrict__ wp,
    const float* __restrict__ gamma, const float* __restrict__ beta,
    const float* __restrict__ mean, const float* __restrict__ rstd,
    unsigned short* __restrict__ wqb, unsigned short* __restrict__ wkb,
    unsigned short* __restrict__ wvb, unsigned short* __restrict__ wpb,
    float* __restrict__ beq, float* __restrict__ bek, float* __restrict__ bev) {
  const float QSC = 0.0625f * 1.4426950408889634f;   // C^-0.5 * log2(e)
  int o = blockIdx.x, c = threadIdx.x;
  float a = gamma[c] * rstd[c];
  float d = beta[c] - mean[c] * a;
  float wqv = wq[o * C_ + c], wkv = wk[o * C_ + c], wvv = wv[o * C_ + c];
  wqb[o * C_ + c] = f2bf(wqv * a * QSC);
  wkb[o * C_ + c] = f2bf(wkv * a);
  wvb[o * C_ + c] = f2bf(wvv * a);
  wpb[o * C_ + c] = f2bf(wp[o * C_ + c]);
  __shared__ float r0[256], r1[256], r2[256];
  r0[c] = wqv * d; r1[c] = wkv * d; r2[c] = wvv * d; __syncthreads();
  for (int off = 128; off > 0; off >>= 1) {
    if (c < off) { r0[c] += r0[c + off]; r1[c] += r1[c + off]; r2[c] += r2[c + off]; }
    __syncthreads();
  }
  if (c == 0) {
    beq[o] = (bq[o] + r0[0]) * QSC;
    bek[o] = bk[o] + r1[0];
    bev[o] = bv[o] + r2[0];
  }
}

// ---------------- K3: fused x-convert + QKV GEMM; q/k bf16 frags, v FP8 frags ----------------
__global__ __launch_bounds__(256) void qkv(
    const float* __restrict__ x,
    const unsigned short* __restrict__ wqb, const unsigned short* __restrict__ wkb,
    const unsigned short* __restrict__ wvb,
    const float* __restrict__ beq, const float* __restrict__ bek,
    const float* __restrict__ bev,
    unsigned short* __restrict__ qB, unsigned short* __restrict__ kB,
    unsigned char* __restrict__ vB) {
  int b = blockIdx.z, oblk = blockIdx.y, n0 = blockIdx.x * 64;
  int tid = threadIdx.x, w = tid >> 6, l = tid & 63, quad = l >> 4, lq = l & 15;
  int orow = oblk * 64 + w * 16 + lq;

  __shared__ unsigned short XF[16384];   // 32 KB x tile in 16x16 B-frag layout
  __shared__ unsigned short Ls[64][72];  // staging / repack buffer

  // ---- stage x -> XF (4 c-quarters, xt's transpose pattern) ----
  {
    int cw = tid >> 6, nl = tid & 63;
    for (int cq = 0; cq < 4; ++cq) {
#pragma unroll
      for (int rr = 0; rr < 16; ++rr) {
        int c = cq * 64 + cw * 16 + rr;
        Ls[nl][cw * 16 + rr] = f2bf(x[((size_t)b * C_ + c) * N_ + n0 + nl]);
      }
      __syncthreads();
      int n_ = tid >> 2, cs = (tid & 3) * 16;
      s8v v0 = *(const s8v*)(&Ls[n_][cs]);
      s8v v1 = *(const s8v*)(&Ls[n_][cs + 8]);
      int fr = ((n_ >> 4) * 32 + ((cq * 64 + cs) >> 3)) * 128 + (n_ & 15) * 8;
      *(s8v*)(XF + fr) = v0;
      *(s8v*)(XF + fr + 128) = v1;
      __syncthreads();
    }
  }

  f4v aq[4], ak[4], av[4];
#pragma unroll
  for (int nt = 0; nt < 4; ++nt) {
    aq[nt] = (f4v){0.f, 0.f, 0.f, 0.f};
    ak[nt] = (f4v){0.f, 0.f, 0.f, 0.f};
    av[nt] = (f4v){0.f, 0.f, 0.f, 0.f};
  }

#pragma unroll
  for (int kk = 0; kk < 8; ++kk) {
    s8v afq = *(const s8v*)(wqb + (size_t)orow * C_ + kk * 32 + quad * 8);
    s8v afk = *(const s8v*)(wkb + (size_t)orow * C_ + kk * 32 + quad * 8);
    s8v afv = *(const s8v*)(wvb + (size_t)orow * C_ + kk * 32 + quad * 8);
#pragma unroll
    for (int nt = 0; nt < 4; ++nt) {
      s8v bf = *(const s8v*)(XF + (nt * 32 + kk * 4 + quad) * 128 + lq * 8);
      aq[nt] = __builtin_amdgcn_mfma_f32_16x16x32_bf16(afq, bf, aq[nt], 0, 0, 0);
      ak[nt] = __builtin_amdgcn_mfma_f32_16x16x32_bf16(afk, bf, ak[nt], 0, 0, 0);
      av[nt] = __builtin_amdgcn_mfma_f32_16x16x32_bf16(afv, bf, av[nt], 0, 0, 0);
    }
  }

  int obase = oblk * 64;

  // pass 1: q -> qB ; pass 2: k -> kB   (stage [n][c]; read out in 32x32-frag order)
  for (int pass = 0; pass < 2; ++pass) {
    const f4v* acc = (pass == 0) ? aq : ak;
    const float* BE = (pass == 0) ? beq : bek;
    int ob4 = obase + w * 16 + quad * 4;
    float b0 = BE[ob4], b1 = BE[ob4 + 1], b2 = BE[ob4 + 2], b3 = BE[ob4 + 3];
    __syncthreads();
#pragma unroll
    for (int nt = 0; nt < 4; ++nt) {
      unsigned lo = (unsigned)f2bf(acc[nt][0] + b0) | ((unsigned)f2bf(acc[nt][1] + b1) << 16);
      unsigned hi = (unsigned)f2bf(acc[nt][2] + b2) | ((unsigned)f2bf(acc[nt][3] + b3) << 16);
      uint2 pr; pr.x = lo; pr.y = hi;
      *(uint2*)(&Ls[nt * 16 + lq][w * 16 + quad * 4]) = pr;
    }
    __syncthreads();
    {
      unsigned short* dp = (pass == 0) ? qB : kB;
#pragma unroll
      for (int ii = 0; ii < 2; ++ii) {
        int i = tid + ii * 256;
        int g = i >> 8, cs = (i >> 6) & 3, ll = i & 63;
        s8v vv = *(const s8v*)(&Ls[g * 32 + (ll & 31)][cs * 16 + ((ll >> 5) << 3)]);
        // both q and k use the 32-row-group frag layout: (((b*128 + n32)*16 + cs)*512 + ll*8
        size_t dst = (((size_t)b * 128 + (n0 >> 5) + g) * 16 + (obase >> 4) + cs) * 512 + (size_t)ll * 8;
        *(s8v*)(dp + dst) = vv;
      }
    }
  }
  __syncthreads();

  // pass 3: v (stage [c][n] bf16; read out in 32x32 A-frag order, CONVERT TO FP8 e4m3)
#pragma unroll
  for (int nt = 0; nt < 4; ++nt)
#pragma unroll
    for (int r = 0; r < 4; ++r) {
      int o_ = obase + w * 16 + quad * 4 + r;
      Ls[w * 16 + quad * 4 + r][nt * 16 + lq] = f2bf(av[nt][r] + bev[o_]);
    }
  __syncthreads();
  {
#pragma unroll
    for (int ii = 0; ii < 2; ++ii) {
      int i = tid + ii * 256;
      int g = i >> 8, ks = (i >> 6) & 3, ll = i & 63;
      s8v vv = *(const s8v*)(&Ls[g * 32 + (ll & 31)][ks * 16 + ((ll >> 5) << 3)]);
      unsigned w0 = (unsigned)__builtin_amdgcn_cvt_pk_fp8_f32(
          bf2f((unsigned short)vv[0]), bf2f((unsigned short)vv[1]), 0, false);
      w0 = (unsigned)__builtin_amdgcn_cvt_pk_fp8_f32(
          bf2f((unsigned short)vv[2]), bf2f((unsigned short)vv[3]), (int)w0, true);
      unsigned w1 = (unsigned)__builtin_amdgcn_cvt_pk_fp8_f32(
          bf2f((unsigned short)vv[4]), bf2f((unsigned short)vv[5]), 0, false);
      w1 = (unsigned)__builtin_amdgcn_cvt_pk_fp8_f32(
          bf2f((unsigned short)vv[6]), bf2f((unsigned short)vv[7]), (int)w1, true);
      uint2 pr; pr.x = w0; pr.y = w1;
      size_t dst = ((((size_t)b * 8 + (obase >> 5) + g) * 256 + (n0 >> 4) + ks) * 64 + ll) * 8;
      *(uint2*)(vB + dst) = pr;
    }
  }
}

// ---------------- K4: FMHA v8.1 — 32 q-rows/block, 512 blocks, NATURAL 2 blocks/CU ----------------
// r11 failed on one token: __launch_bounds__(512,4) clamped VGPR to 64 -> 700 MB
// of scratch spill. The clamp was never needed: this loop shape compiles at
// ~92-116 VGPR (r10 evidence), and at <=128 VGPR + 34 KB LDS the hardware
// schedules 2 resident blocks/CU on its own (waves/CU halve at 64/128/256).
// So: same halved-tile structure, __launch_bounds__(512,2) (cap 256, no clamp).
// 2 independent blocks/CU -> 4 waves/SIMD; one block's barrier/vmcnt stalls
// hide under the other's issue (m114) — the TLP attack on the serialized
// critical path measured in r10 (~10.8k cyc/chunk invariant to traffic cuts).
__global__ __launch_bounds__(512, 2) void attn(
    const unsigned short* __restrict__ qB, const unsigned short* __restrict__ kB,
    const unsigned char* __restrict__ vB,
    const unsigned short* __restrict__ wpb, const float* __restrict__ bp,
    const float* __restrict__ x, float* __restrict__ out) {
  int id = blockIdx.x;                       // 512 blocks; id&7 = XCD (2 XCDs per batch)
  int b = (id & 7) >> 1;
  int r32 = ((id >> 3) << 1) | (id & 1);     // 32-row tile index within batch [0,128)
  int i0 = r32 << 5;
  int tid = threadIdx.x, w = tid >> 6, l = tid & 63;
  int lh = l >> 5, l31 = l & 31;

  __shared__ unsigned short Qs[8192];        // 16 KB q-tile; REUSED as proj-input tile
  __shared__ unsigned char Ps[2][8192];      // 2 x 8 KB P tiles (fp8)
  __shared__ float Lw[8][32];

  // stage q-tile (contiguous 16 KB = 1024 s8v fragments in qB)
  {
    const s8v* g = (const s8v*)(qB + (((size_t)b * 128 + r32) * 16) * 512);
    s8v* sq = (s8v*)Qs;
    sq[tid] = g[tid];
    sq[tid + 512] = g[tid + 512];
  }

  // K: wave w owns key32-group w of each chunk; advance 8 groups = 65536 elems/chunk
  const unsigned short* kp = kB + (((size_t)b * 128 + w) * 16) * 512 + (size_t)l * 8;
  // V (fp8, BYTE addressing): wave w owns channel-group w; frag ks at +ks*512 B
  const unsigned char* vp = vB + (((size_t)b * 8 + w) * 256) * 512 + (size_t)l * 8;
  const unsigned short* Qp = Qs + (size_t)l * 8;   // + cs*512

  // prologue: kf for chunk 0
  s8v kf[16];
#pragma unroll
  for (int cs = 0; cs < 16; ++cs) kf[cs] = *(const s8v*)(kp + cs * 512);
  SCHED_FENCE();

  __syncthreads();  // Qs visible

  f16v O0 = zf16();   // channels w*32+chl, rows i0+l31
  float ls0 = 0.f;

  for (int t = 0; t < 16; ++t) {
    // ---- S phase: this wave's 32 keys x 32 rows (bf16 MFMA) ----
    f16v S0 = zf16();
    __builtin_amdgcn_s_setprio(1);
#pragma unroll
    for (int cs = 0; cs < 16; ++cs) {
      s8v q0 = *(const s8v*)(Qp + cs * 512);
      S0 = __builtin_amdgcn_mfma_f32_32x32x16_bf16(kf[cs], q0, S0, 0, 0, 0);
    }
    __builtin_amdgcn_s_setprio(0);
    SCHED_FENCE();
    // ---- vf prefetch for THIS chunk (fp8, 32 VGPR); latency covered by exp+barrier ----
    i64f vf[16];
#pragma unroll
    for (int ks = 0; ks < 16; ++ks) vf[ks] = *(const i64f*)(vp + ks * 512);
    vp += 8192;
    SCHED_FENCE();
    // ---- exp2 + fp8 pack + P write. key = w*32 + 8j + 4lh + (0..3), row = l31 ----
    unsigned char* Pw = Ps[t & 1] + w * 1024 + l31 * 8 + lh * 4;
#pragma unroll
    for (int j = 0; j < 4; ++j) {
      float a0 = EXP2(S0[4 * j + 0]), a1 = EXP2(S0[4 * j + 1]);
      float a2 = EXP2(S0[4 * j + 2]), a3 = EXP2(S0[4 * j + 3]);
      ls0 += (a0 + a1) + (a2 + a3);
      unsigned p0 = (unsigned)__builtin_amdgcn_cvt_pk_fp8_f32(a0, a1, 0, false);
      p0 = (unsigned)__builtin_amdgcn_cvt_pk_fp8_f32(a2, a3, (int)p0, true);
      *(unsigned*)(Pw + j * 256) = p0;
    }
    __syncthreads();   // P visible
    // ---- kf prefetch for NEXT chunk (lands during PV; t=15 read is benign OOB) ----
    kp += 65536;
#pragma unroll
    for (int cs = 0; cs < 16; ++cs) kf[cs] = *(const s8v*)(kp + cs * 512);
    SCHED_FENCE();
    // ---- PV phase: fp8 MFMA; this wave's 32 channels, all 256 keys ----
    const unsigned char* Pr = Ps[t & 1] + (size_t)lh * 256 + l31 * 8;
    __builtin_amdgcn_s_setprio(1);
#pragma unroll
    for (int ks = 0; ks < 16; ++ks) {
      i64f p0 = *(const i64f*)(Pr + ks * 512);
      O0 = __builtin_amdgcn_mfma_f32_32x32x16_fp8_fp8(vf[ks], p0, O0, 0, 0, 0);
    }
    __builtin_amdgcn_s_setprio(0);
  }

  // ---- wp A-frag prefetch (kf/vf dead now; lands under the reductions) ----
  s8v wf[16];
#pragma unroll
  for (int cs = 0; cs < 16; ++cs)
    wf[cs] = *(const s8v*)(wpb + (size_t)(w * 32 + l31) * 256 + cs * 16 + lh * 8);
  SCHED_FENCE();

  // lsum: lane holds the sums for row l31 over its 16 keys/chunk; l^32 has the rest
  ls0 += __shfl_xor(ls0, 32);
  if (l < 32) Lw[w][l] = ls0;
  __syncthreads();
  float s0 = 0.f;
#pragma unroll
  for (int ww = 0; ww < 8; ++ww) s0 += Lw[ww][l31];
  float rl0 = 1.f / s0;

  // ---- normalize + write attn-out tile to LDS (aliases Qs; 16x16 B-frag, 32 rows) ----
  unsigned short* aS = Qs;
#pragma unroll
  for (int jj = 0; jj < 4; ++jj) {
    ushort4 pk;
    pk.x = f2bf(O0[4 * jj + 0] * rl0); pk.y = f2bf(O0[4 * jj + 1] * rl0);
    pk.z = f2bf(O0[4 * jj + 2] * rl0); pk.w = f2bf(O0[4 * jj + 3] * rl0);
    int f0 = ((l31 >> 4) * 32 + w * 4 + jj) * 128 + (l31 & 15) * 8 + lh * 4;
    *(ushort4*)(aS + f0) = pk;
  }
  __syncthreads();   // aS visible

  // ---- projection GEMM: out[o][n] = sum_c wp[o][c] * a[c][n], n = i0 + l31 ----
  f16v OP0 = zf16();
#pragma unroll
  for (int cs = 0; cs < 16; ++cs) {
    s8v pa0 = *(const s8v*)(aS + ((l31 >> 4) * 32 + cs * 2 + lh) * 128 + (l31 & 15) * 8);
    OP0 = __builtin_amdgcn_mfma_f32_32x32x16_bf16(wf[cs], pa0, OP0, 0, 0, 0);
  }

  // ---- epilogue: out = x + proj + bp ----
#pragma unroll
  for (int r = 0; r < 16; ++r) {
    int o_ = w * 32 + (r & 3) + 8 * (r >> 2) + 4 * lh;
    size_t ix = ((size_t)b * C_ + o_) * N_ + i0 + l31;
    out[ix] = x[ix] + OP0[r] + bp[o_];
  }
}

extern "C" void kernel_launch(void* const* d_in, const int* in_sizes, int n_in,
                              void* d_out, int out_size, void* d_ws, size_t ws_size,
                              hipStream_t stream) {
  const float* x     = (const float*)d_in[0];
  const float* gamma = (const float*)d_in[1];
  const float* beta  = (const float*)d_in[2];
  const float* wq    = (const float*)d_in[3];
  const float* bq    = (const float*)d_in[4];
  const float* wk    = (const float*)d_in[5];
  const float* bk    = (const float*)d_in[6];
  const float* wv    = (const float*)d_in[7];
  const float* bv    = (const float*)d_in[8];
  const float* wp    = (const float*)d_in[9];
  const float* bp    = (const float*)d_in[10];
  float* out = (float*)d_out;

  char* ws = (char*)d_ws;
  float* mean = (float*)ws; ws += 1024;
  float* rstd = (float*)ws; ws += 1024;
  float* beq  = (float*)ws; ws += 1024;
  float* bek  = (float*)ws; ws += 1024;
  float* bev  = (float*)ws; ws += 1024;
  unsigned short* wqb = (unsigned short*)ws; ws += C_ * C_ * 2;
  unsigned short* wkb = (unsigned short*)ws; ws += C_ * C_ * 2;
  unsigned short* wvb = (unsigned short*)ws; ws += C_ * C_ * 2;
  unsigned short* wpb = (unsigned short*)ws; ws += C_ * C_ * 2;
  unsigned short* qB  = (unsigned short*)ws; ws += (size_t)B_ * N_ * C_ * 2;
  unsigned short* kB  = (unsigned short*)ws; ws += (size_t)B_ * N_ * C_ * 2;
  unsigned char*  vB  = (unsigned char*)ws;  ws += (size_t)B_ * N_ * C_ * 2;  // fp8 uses half; slack absorbs OOB prefetch

  hipLaunchKernelGGL(bn_stats, dim3(C_), dim3(256), 0, stream, x, mean, rstd);
  hipLaunchKernelGGL(prep, dim3(C_), dim3(256), 0, stream,
                     wq, bq, wk, bk, wv, bv, wp, gamma, beta, mean, rstd,
                     wqb, wkb, wvb, wpb, beq, bek, bev);
  hipLaunchKernelGGL(qkv, dim3(N_ / 64, 4, B_), dim3(256), 0, stream,
                     x, wqb, wkb, wvb, beq, bek, bev, qB, kB, vB);
  hipLaunchKernelGGL(attn, dim3(512), dim3(512), 0, stream,
                     qB, kB, vB, wpb, bp, x, out);
}

// Round 13
// 189.392 us; speedup vs baseline: 2.0450x; 1.1326x over previous
//
#include <hip/hip_runtime.h>
#include <cstdint>
#include <cstddef>

#define B_ 4
#define C_ 256
#define N_ 4096

typedef __attribute__((ext_vector_type(8))) short s8v;    // 8 bf16 (4 VGPRs) MFMA A/B frag
typedef __attribute__((ext_vector_type(4))) float f4v;    // 16x16 MFMA C/D frag
typedef __attribute__((ext_vector_type(16))) float f16v;  // 32x32 MFMA C/D frag
typedef long long i64f;                                   // 8 fp8 (2 VGPRs) MFMA A/B frag

#if defined(__has_builtin)
#if __has_builtin(__builtin_amdgcn_exp2f)
#define EXP2(x) __builtin_amdgcn_exp2f(x)
#endif
#endif
#ifndef EXP2
#define EXP2(x) exp2f(x)
#endif

// scheduling fence: no instruction may be reordered across (pins prefetch issue)
#define SCHED_FENCE() __builtin_amdgcn_sched_barrier(0)

__device__ __forceinline__ unsigned short f2bf(float f) {
  unsigned int u = __builtin_bit_cast(unsigned int, f);
  return (unsigned short)((u + 0x7FFFu + ((u >> 16) & 1u)) >> 16);  // RNE
}

__device__ __forceinline__ float bf2f(unsigned short u) {
  return __builtin_bit_cast(float, (unsigned)u << 16);
}

__device__ __forceinline__ f16v zf16() {
  f16v z;
#pragma unroll
  for (int i = 0; i < 16; ++i) z[i] = 0.f;
  return z;
}

// Layouts:
//  16x16 B-frag blocked bf16 (aS LDS tile): flat = ((n>>4)*32 + (c>>3))*128 + (n&15)*8 + (c&7)
//  qB/kB bf16 (32x32 frag, unified 32-row groups): flat = (((b*128 + n32)*16 + cs)*64 + l)*8 + e
//      q: holds q[c = cs*16 + (l>>5)*8 + e][n = n32*32 + (l&31)]  (k identical)
//  vB FP8 e4m3 (BYTE units): byte = (((b*8 + cg)*256 + ks)*64 + l)*8 + e
//  P LDS fp8 (64 rows, 2 rg): byte = k8*512 + (l31)*8 + klow (+8192 for rg=1)

// ---------------- K1: BatchNorm statistics ----------------
__global__ __launch_bounds__(256) void bn_stats(const float* __restrict__ x,
                                                float* __restrict__ mean,
                                                float* __restrict__ rstd) {
  int c = blockIdx.x, t = threadIdx.x;
  float s = 0.f, s2 = 0.f;
  for (int b = 0; b < B_; ++b) {
    const float* p = x + ((size_t)b * C_ + c) * N_;
    for (int n = t * 4; n < N_; n += 1024) {
      float4 v = *(const float4*)(p + n);
      s += (v.x + v.y) + (v.z + v.w);
      s2 += (v.x * v.x + v.y * v.y) + (v.z * v.z + v.w * v.w);
    }
  }
  __shared__ float rs[256], rs2[256];
  rs[t] = s; rs2[t] = s2; __syncthreads();
  for (int off = 128; off > 0; off >>= 1) {
    if (t < off) { rs[t] += rs[t + off]; rs2[t] += rs2[t + off]; }
    __syncthreads();
  }
  if (t == 0) {
    float m = rs[0] * (1.f / 16384.f);
    float v = rs2[0] * (1.f / 16384.f) - m * m;
    mean[c] = m; rstd[c] = rsqrtf(v + 1e-5f);
  }
}

// ---------------- K2: fold BN (and C^-0.5 * log2e into q path) into weights ----------------
__global__ __launch_bounds__(256) void prep(
    const float* __restrict__ wq, const float* __restrict__ bq,
    const float* __restrict__ wk, const float* __restrict__ bk,
    const float* __restrict__ wv, const float* __restrict__ bv,
    const float* __restrict__ wp,
    const float* __restrict__ gamma, const float* __restrict__ beta,
    const float* __restrict__ mean, const float* __restrict__ rstd,
    unsigned short* __restrict__ wqb, unsigned short* __restrict__ wkb,
    unsigned short* __restrict__ wvb, unsigned short* __restrict__ wpb,
    float* __restrict__ beq, float* __restrict__ bek, float* __restrict__ bev) {
  const float QSC = 0.0625f * 1.4426950408889634f;   // C^-0.5 * log2(e)
  int o = blockIdx.x, c = threadIdx.x;
  float a = gamma[c] * rstd[c];
  float d = beta[c] - mean[c] * a;
  float wqv = wq[o * C_ + c], wkv = wk[o * C_ + c], wvv = wv[o * C_ + c];
  wqb[o * C_ + c] = f2bf(wqv * a * QSC);
  wkb[o * C_ + c] = f2bf(wkv * a);
  wvb[o * C_ + c] = f2bf(wvv * a);
  wpb[o * C_ + c] = f2bf(wp[o * C_ + c]);
  __shared__ float r0[256], r1[256], r2[256];
  r0[c] = wqv * d; r1[c] = wkv * d; r2[c] = wvv * d; __syncthreads();
  for (int off = 128; off > 0; off >>= 1) {
    if (c < off) { r0[c] += r0[c + off]; r1[c] += r1[c + off]; r2[c] += r2[c + off]; }
    __syncthreads();
  }
  if (c == 0) {
    beq[o] = (bq[o] + r0[0]) * QSC;
    bek[o] = bk[o] + r1[0];
    bev[o] = bv[o] + r2[0];
  }
}

// ---------------- K3: fused x-convert + QKV GEMM (single-stage LDS) ----------------
// x staged ONCE into Ls[64][264] in plain [n][c] layout (row stride 528 B:
// 16B-aligned for b128 frag reads; bank-stride 4 -> frag reads are uniform
// 8-cycle). MFMA B-frags read DIRECTLY from Ls (same data the old XF held) —
// the XF tile, the second LDS round-trip, and 7 of the 8 staging barriers are
// gone. Repack/store passes reuse Ls memory (x is dead after the MFMA loop).
__global__ __launch_bounds__(256) void qkv(
    const float* __restrict__ x,
    const unsigned short* __restrict__ wqb, const unsigned short* __restrict__ wkb,
    const unsigned short* __restrict__ wvb,
    const float* __restrict__ beq, const float* __restrict__ bek,
    const float* __restrict__ bev,
    unsigned short* __restrict__ qB, unsigned short* __restrict__ kB,
    unsigned char* __restrict__ vB) {
  int b = blockIdx.z, oblk = blockIdx.y, n0 = blockIdx.x * 64;
  int tid = threadIdx.x, w = tid >> 6, l = tid & 63, quad = l >> 4, lq = l & 15;
  int orow = oblk * 64 + w * 16 + lq;

  __shared__ unsigned short Ls[64][264];   // 33.8 KB x tile [n][c]

  // ---- stage x -> Ls (ONE barrier) ----
  {
    int cw = tid >> 6, nl = tid & 63;
    const float* xp = x + ((size_t)b * C_ + cw * 64) * N_ + n0 + nl;
#pragma unroll
    for (int i = 0; i < 32; ++i) {
      float f0 = xp[(size_t)(2 * i) * N_];
      float f1 = xp[(size_t)(2 * i + 1) * N_];
      unsigned pk = (unsigned)f2bf(f0) | ((unsigned)f2bf(f1) << 16);
      *(unsigned*)(&Ls[nl][cw * 64 + 2 * i]) = pk;
    }
  }
  __syncthreads();

  f4v aq[4], ak[4], av[4];
#pragma unroll
  for (int nt = 0; nt < 4; ++nt) {
    aq[nt] = (f4v){0.f, 0.f, 0.f, 0.f};
    ak[nt] = (f4v){0.f, 0.f, 0.f, 0.f};
    av[nt] = (f4v){0.f, 0.f, 0.f, 0.f};
  }

#pragma unroll
  for (int kk = 0; kk < 8; ++kk) {
    s8v afq = *(const s8v*)(wqb + (size_t)orow * C_ + kk * 32 + quad * 8);
    s8v afk = *(const s8v*)(wkb + (size_t)orow * C_ + kk * 32 + quad * 8);
    s8v afv = *(const s8v*)(wvb + (size_t)orow * C_ + kk * 32 + quad * 8);
#pragma unroll
    for (int nt = 0; nt < 4; ++nt) {
      s8v bf = *(const s8v*)(&Ls[nt * 16 + lq][kk * 32 + quad * 8]);
      aq[nt] = __builtin_amdgcn_mfma_f32_16x16x32_bf16(afq, bf, aq[nt], 0, 0, 0);
      ak[nt] = __builtin_amdgcn_mfma_f32_16x16x32_bf16(afk, bf, ak[nt], 0, 0, 0);
      av[nt] = __builtin_amdgcn_mfma_f32_16x16x32_bf16(afv, bf, av[nt], 0, 0, 0);
    }
  }

  int obase = oblk * 64;
  unsigned short (*Lr)[72] = (unsigned short(*)[72])Ls;   // repack view (x dead)

  // pass 1: q -> qB ; pass 2: k -> kB   (stage [n][c]; read out in 32x32-frag order)
  for (int pass = 0; pass < 2; ++pass) {
    const f4v* acc = (pass == 0) ? aq : ak;
    const float* BE = (pass == 0) ? beq : bek;
    int ob4 = obase + w * 16 + quad * 4;
    float b0 = BE[ob4], b1 = BE[ob4 + 1], b2 = BE[ob4 + 2], b3 = BE[ob4 + 3];
    __syncthreads();
#pragma unroll
    for (int nt = 0; nt < 4; ++nt) {
      unsigned lo = (unsigned)f2bf(acc[nt][0] + b0) | ((unsigned)f2bf(acc[nt][1] + b1) << 16);
      unsigned hi = (unsigned)f2bf(acc[nt][2] + b2) | ((unsigned)f2bf(acc[nt][3] + b3) << 16);
      uint2 pr; pr.x = lo; pr.y = hi;
      *(uint2*)(&Lr[nt * 16 + lq][w * 16 + quad * 4]) = pr;
    }
    __syncthreads();
    {
      unsigned short* dp = (pass == 0) ? qB : kB;
#pragma unroll
      for (int ii = 0; ii < 2; ++ii) {
        int i = tid + ii * 256;
        int g = i >> 8, cs = (i >> 6) & 3, ll = i & 63;
        s8v vv = *(const s8v*)(&Lr[g * 32 + (ll & 31)][cs * 16 + ((ll >> 5) << 3)]);
        // unified 32-row-group frag layout
        size_t dst = (((size_t)b * 128 + (n0 >> 5) + g) * 16 + (obase >> 4) + cs) * 512 + (size_t)ll * 8;
        *(s8v*)(dp + dst) = vv;
      }
    }
  }
  __syncthreads();

  // pass 3: v (stage [c][n] bf16; read out in 32x32 A-frag order, CONVERT TO FP8 e4m3)
#pragma unroll
  for (int nt = 0; nt < 4; ++nt)
#pragma unroll
    for (int r = 0; r < 4; ++r) {
      int o_ = obase + w * 16 + quad * 4 + r;
      Lr[w * 16 + quad * 4 + r][nt * 16 + lq] = f2bf(av[nt][r] + bev[o_]);
    }
  __syncthreads();
  {
#pragma unroll
    for (int ii = 0; ii < 2; ++ii) {
      int i = tid + ii * 256;
      int g = i >> 8, ks = (i >> 6) & 3, ll = i & 63;
      s8v vv = *(const s8v*)(&Lr[g * 32 + (ll & 31)][ks * 16 + ((ll >> 5) << 3)]);
      unsigned w0 = (unsigned)__builtin_amdgcn_cvt_pk_fp8_f32(
          bf2f((unsigned short)vv[0]), bf2f((unsigned short)vv[1]), 0, false);
      w0 = (unsigned)__builtin_amdgcn_cvt_pk_fp8_f32(
          bf2f((unsigned short)vv[2]), bf2f((unsigned short)vv[3]), (int)w0, true);
      unsigned w1 = (unsigned)__builtin_amdgcn_cvt_pk_fp8_f32(
          bf2f((unsigned short)vv[4]), bf2f((unsigned short)vv[5]), 0, false);
      w1 = (unsigned)__builtin_amdgcn_cvt_pk_fp8_f32(
          bf2f((unsigned short)vv[6]), bf2f((unsigned short)vv[7]), (int)w1, true);
      uint2 pr; pr.x = w0; pr.y = w1;
      size_t dst = ((((size_t)b * 8 + (obase >> 5) + g) * 256 + (n0 >> 4) + ks) * 64 + ll) * 8;
      *(uint2*)(vB + dst) = pr;
    }
  }
}

// ---------------- K4: FMHA (r10 exact: 64 q-rows, fp8 P/V, fused projection) ----------------
__global__ __launch_bounds__(512, 2) void attn(
    const unsigned short* __restrict__ qB, const unsigned short* __restrict__ kB,
    const unsigned char* __restrict__ vB,
    const unsigned short* __restrict__ wpb, const float* __restrict__ bp,
    const float* __restrict__ x, float* __restrict__ out) {
  int id = blockIdx.x;                       // id&7 = XCD (2 XCDs per batch)
  int b = (id & 7) >> 1;
  int i0 = (((id >> 3) << 1) | (id & 1)) << 6;   // 64 q-rows per block
  int tid = threadIdx.x, w = tid >> 6, l = tid & 63;
  int lh = l >> 5, l31 = l & 31;

  __shared__ unsigned short Qs[16384];       // 32 KB q-tile (bf16)
  __shared__ unsigned char Ps[2][16384];     // 2 x 16 KB P tiles (fp8)
  __shared__ unsigned short aS[16384];       // 32 KB attn-out tile (bf16, proj input)
  __shared__ float Lw[8][2][32];

  // stage q-tile (contiguous 32 KB = 2048 s8v fragments in qB)
  {
    const s8v* g = (const s8v*)(qB + ((size_t)b * 64 + (i0 >> 6)) * 16384);
    s8v* sq = (s8v*)Qs;
    sq[tid] = g[tid];
    sq[tid + 512] = g[tid + 512];
    sq[tid + 1024] = g[tid + 1024];
    sq[tid + 1536] = g[tid + 1536];
  }

  // K: wave w owns key32-group w of each chunk; advance 8 groups = 65536 elems/chunk
  const unsigned short* kp = kB + (((size_t)b * 128 + w) * 16) * 512 + (size_t)l * 8;
  // V (fp8, BYTE addressing): wave w owns channel-group w; frag ks at +ks*512 B
  const unsigned char* vp = vB + (((size_t)b * 8 + w) * 256) * 512 + (size_t)l * 8;
  const unsigned short* Qp = Qs + (size_t)lh * 256 + l31 * 8;   // + rg*8192 + cs*512

  // prologue: kf for chunk 0 (pinned before the barrier)
  s8v kf[16];
#pragma unroll
  for (int cs = 0; cs < 16; ++cs) kf[cs] = *(const s8v*)(kp + cs * 512);
  SCHED_FENCE();

  __syncthreads();  // Qs visible

  f16v O0 = zf16(), O1 = zf16();   // [rg] channels w*32+chl, rows i0+rg*32+l31
  float ls0 = 0.f, ls1 = 0.f;

  for (int t = 0; t < 16; ++t) {
    // ---- vf prefetch for THIS chunk (fp8: 16 x 8 B = 32 VGPR) ----
    i64f vf[16];
#pragma unroll
    for (int ks = 0; ks < 16; ++ks) vf[ks] = *(const i64f*)(vp + ks * 512);
    SCHED_FENCE();
    // ---- S phase: this wave's 32 keys x 64 rows (bf16 MFMA) ----
    f16v S0 = zf16(), S1 = zf16();
    __builtin_amdgcn_s_setprio(1);
#pragma unroll
    for (int cs = 0; cs < 16; ++cs) {
      s8v q0 = *(const s8v*)(Qp + cs * 512);
      s8v q1 = *(const s8v*)(Qp + 8192 + cs * 512);
      S0 = __builtin_amdgcn_mfma_f32_32x32x16_bf16(kf[cs], q0, S0, 0, 0, 0);
      S1 = __builtin_amdgcn_mfma_f32_32x32x16_bf16(kf[cs], q1, S1, 0, 0, 0);
    }
    __builtin_amdgcn_s_setprio(0);
    SCHED_FENCE();
    // ---- exp2 + fp8 pack + P write. key = w*32 + 8j + 4lh + (0..3), row = rg*32+l31 ----
    unsigned char* Pw = Ps[t & 1] + (w * 4) * 512 + l31 * 8 + lh * 4;
#pragma unroll
    for (int j = 0; j < 4; ++j) {
      float a0 = EXP2(S0[4 * j + 0]), a1 = EXP2(S0[4 * j + 1]);
      float a2 = EXP2(S0[4 * j + 2]), a3 = EXP2(S0[4 * j + 3]);
      ls0 += (a0 + a1) + (a2 + a3);
      unsigned p0 = (unsigned)__builtin_amdgcn_cvt_pk_fp8_f32(a0, a1, 0, false);
      p0 = (unsigned)__builtin_amdgcn_cvt_pk_fp8_f32(a2, a3, (int)p0, true);
      *(unsigned*)(Pw + j * 512) = p0;
      float c0 = EXP2(S1[4 * j + 0]), c1 = EXP2(S1[4 * j + 1]);
      float c2 = EXP2(S1[4 * j + 2]), c3 = EXP2(S1[4 * j + 3]);
      ls1 += (c0 + c1) + (c2 + c3);
      unsigned p1 = (unsigned)__builtin_amdgcn_cvt_pk_fp8_f32(c0, c1, 0, false);
      p1 = (unsigned)__builtin_amdgcn_cvt_pk_fp8_f32(c2, c3, (int)p1, true);
      *(unsigned*)(Pw + j * 512 + 256) = p1;
    }
    __syncthreads();   // P visible; vf landed (issued before S)
    // ---- kf prefetch for NEXT chunk (t=15 read is benign OOB into vB) ----
    kp += 65536;
#pragma unroll
    for (int cs = 0; cs < 16; ++cs) kf[cs] = *(const s8v*)(kp + cs * 512);
    SCHED_FENCE();
    // ---- PV phase: fp8 MFMA; this wave's 32 channels, all 256 keys ----
    const unsigned char* Pr = Ps[t & 1] + (size_t)lh * 512 + l31 * 8;
    __builtin_amdgcn_s_setprio(1);
#pragma unroll
    for (int ks = 0; ks < 16; ++ks) {
      i64f p0 = *(const i64f*)(Pr + ks * 1024);
      i64f p1 = *(const i64f*)(Pr + ks * 1024 + 256);
      O0 = __builtin_amdgcn_mfma_f32_32x32x16_fp8_fp8(vf[ks], p0, O0, 0, 0, 0);
      O1 = __builtin_amdgcn_mfma_f32_32x32x16_fp8_fp8(vf[ks], p1, O1, 0, 0, 0);
    }
    __builtin_amdgcn_s_setprio(0);
    vp += 8192;
  }

  // ---- wp A-frag prefetch (registers free now; lands under the reductions) ----
  s8v wf[16];
#pragma unroll
  for (int cs = 0; cs < 16; ++cs)
    wf[cs] = *(const s8v*)(wpb + (size_t)(w * 32 + l31) * 256 + cs * 16 + lh * 8);
  SCHED_FENCE();

  // lsum: lane has sum over its 16 keys/chunk; partner lane (l^32) has the other 16
  ls0 += __shfl_xor(ls0, 32);
  ls1 += __shfl_xor(ls1, 32);
  if (l < 32) { Lw[w][0][l] = ls0; Lw[w][1][l] = ls1; }
  __syncthreads();
  float s0 = 0.f, s1 = 0.f;
#pragma unroll
  for (int ww = 0; ww < 8; ++ww) { s0 += Lw[ww][0][l31]; s1 += Lw[ww][1][l31]; }
  float rl0 = 1.f / s0, rl1 = 1.f / s1;

  // ---- normalize + write attn-out tile to LDS (bf16 16x16 B-frag, tile-local) ----
#pragma unroll
  for (int jj = 0; jj < 4; ++jj) {
    ushort4 pk;
    pk.x = f2bf(O0[4 * jj + 0] * rl0); pk.y = f2bf(O0[4 * jj + 1] * rl0);
    pk.z = f2bf(O0[4 * jj + 2] * rl0); pk.w = f2bf(O0[4 * jj + 3] * rl0);
    int f0 = ((l31 >> 4) * 32 + w * 4 + jj) * 128 + (l31 & 15) * 8 + lh * 4;
    *(ushort4*)(aS + f0) = pk;
    pk.x = f2bf(O1[4 * jj + 0] * rl1); pk.y = f2bf(O1[4 * jj + 1] * rl1);
    pk.z = f2bf(O1[4 * jj + 2] * rl1); pk.w = f2bf(O1[4 * jj + 3] * rl1);
    int f1 = ((2 + (l31 >> 4)) * 32 + w * 4 + jj) * 128 + (l31 & 15) * 8 + lh * 4;
    *(ushort4*)(aS + f1) = pk;
  }
  __syncthreads();   // aS visible

  // ---- projection GEMM: out[o][n] = sum_c wp[o][c] * a[c][n] ----
  f16v OP0 = zf16(), OP1 = zf16();
#pragma unroll
  for (int cs = 0; cs < 16; ++cs) {
    s8v pa0 = *(const s8v*)(aS + ((0 + (l31 >> 4)) * 32 + cs * 2 + lh) * 128 + (l31 & 15) * 8);
    s8v pa1 = *(const s8v*)(aS + ((2 + (l31 >> 4)) * 32 + cs * 2 + lh) * 128 + (l31 & 15) * 8);
    OP0 = __builtin_amdgcn_mfma_f32_32x32x16_bf16(wf[cs], pa0, OP0, 0, 0, 0);
    OP1 = __builtin_amdgcn_mfma_f32_32x32x16_bf16(wf[cs], pa1, OP1, 0, 0, 0);
  }

  // ---- epilogue: out = x + proj + bp ----
#pragma unroll
  for (int r = 0; r < 16; ++r) {
    int o_ = w * 32 + (r & 3) + 8 * (r >> 2) + 4 * lh;
    float bpv = bp[o_];
    size_t ix = ((size_t)b * C_ + o_) * N_ + i0 + l31;
    out[ix]      = x[ix]      + OP0[r] + bpv;
    out[ix + 32] = x[ix + 32] + OP1[r] + bpv;
  }
}

extern "C" void kernel_launch(void* const* d_in, const int* in_sizes, int n_in,
                              void* d_out, int out_size, void* d_ws, size_t ws_size,
                              hipStream_t stream) {
  const float* x     = (const float*)d_in[0];
  const float* gamma = (const float*)d_in[1];
  const float* beta  = (const float*)d_in[2];
  const float* wq    = (const float*)d_in[3];
  const float* bq    = (const float*)d_in[4];
  const float* wk    = (const float*)d_in[5];
  const float* bk    = (const float*)d_in[6];
  const float* wv    = (const float*)d_in[7];
  const float* bv    = (const float*)d_in[8];
  const float* wp    = (const float*)d_in[9];
  const float* bp    = (const float*)d_in[10];
  float* out = (float*)d_out;

  char* ws = (char*)d_ws;
  float* mean = (float*)ws; ws += 1024;
  float* rstd = (float*)ws; ws += 1024;
  float* beq  = (float*)ws; ws += 1024;
  float* bek  = (float*)ws; ws += 1024;
  float* bev  = (float*)ws; ws += 1024;
  unsigned short* wqb = (unsigned short*)ws; ws += C_ * C_ * 2;
  unsigned short* wkb = (unsigned short*)ws; ws += C_ * C_ * 2;
  unsigned short* wvb = (unsigned short*)ws; ws += C_ * C_ * 2;
  unsigned short* wpb = (unsigned short*)ws; ws += C_ * C_ * 2;
  unsigned short* qB  = (unsigned short*)ws; ws += (size_t)B_ * N_ * C_ * 2;
  unsigned short* kB  = (unsigned short*)ws; ws += (size_t)B_ * N_ * C_ * 2;
  unsigned char*  vB  = (unsigned char*)ws;  ws += (size_t)B_ * N_ * C_ * 2;  // fp8 uses half; slack absorbs OOB prefetch

  hipLaunchKernelGGL(bn_stats, dim3(C_), dim3(256), 0, stream, x, mean, rstd);
  hipLaunchKernelGGL(prep, dim3(C_), dim3(256), 0, stream,
                     wq, bq, wk, bk, wv, bv, wp, gamma, beta, mean, rstd,
                     wqb, wkb, wvb, wpb, beq, bek, bev);
  hipLaunchKernelGGL(qkv, dim3(N_ / 64, 4, B_), dim3(256), 0, stream,
                     x, wqb, wkb, wvb, beq, bek, bev, qB, kB, vB);
  hipLaunchKernelGGL(attn, dim3(256), dim3(512), 0, stream,
                     qB, kB, vB, wpb, bp, x, out);
}

// Round 14
// 176.128 us; speedup vs baseline: 2.1990x; 1.0753x over previous
//
#include <hip/hip_runtime.h>
#include <cstdint>
#include <cstddef>

#define B_ 4
#define C_ 256
#define N_ 4096

typedef __attribute__((ext_vector_type(8))) short s8v;    // 8 bf16 (4 VGPRs) MFMA A/B frag
typedef __attribute__((ext_vector_type(4))) float f4v;    // 16x16 MFMA C/D frag
typedef __attribute__((ext_vector_type(16))) float f16v;  // 32x32 MFMA C/D frag
typedef long long i64f;                                   // 8 fp8 (2 VGPRs) MFMA A/B frag

#if defined(__has_builtin)
#if __has_builtin(__builtin_amdgcn_exp2f)
#define EXP2(x) __builtin_amdgcn_exp2f(x)
#endif
#endif
#ifndef EXP2
#define EXP2(x) exp2f(x)
#endif

// scheduling fence: no instruction may be reordered across (pins prefetch issue)
#define SCHED_FENCE() __builtin_amdgcn_sched_barrier(0)

__device__ __forceinline__ unsigned short f2bf(float f) {
  unsigned int u = __builtin_bit_cast(unsigned int, f);
  return (unsigned short)((u + 0x7FFFu + ((u >> 16) & 1u)) >> 16);  // RNE
}

__device__ __forceinline__ float bf2f(unsigned short u) {
  return __builtin_bit_cast(float, (unsigned)u << 16);
}

__device__ __forceinline__ f16v zf16() {
  f16v z;
#pragma unroll
  for (int i = 0; i < 16; ++i) z[i] = 0.f;
  return z;
}

// Layouts:
//  16x16 B-frag blocked bf16 (aS LDS tile): flat = ((n>>4)*32 + (c>>3))*128 + (n&15)*8 + (c&7)
//  qB/kB FP8 e4m3 (32x32x16 fp8 frags, BYTE units; identical (k,n) index mapping
//    to the old bf16 frags, 8 bytes per lane): byte = (frag_idx)*512 + l*8
//    q frag_idx = ((b*128 + n32)*16 + cs) ; k frag_idx = ((b*128 + kg)*16 + cs)
//  vB FP8 e4m3 (BYTE units): byte = (((b*8 + cg)*256 + ks)*64 + l)*8 + e
//  P LDS fp8 (64 rows, 2 rg): byte = k8*512 + l31*8 + klow (+256 for rg=1)
//  NOTE: sqrt(C^-0.5 * log2e) folded into BOTH wq and wk (fp8 dynamic range).

// ---------------- K1: BatchNorm statistics ----------------
__global__ __launch_bounds__(256) void bn_stats(const float* __restrict__ x,
                                                float* __restrict__ mean,
                                                float* __restrict__ rstd) {
  int c = blockIdx.x, t = threadIdx.x;
  float s = 0.f, s2 = 0.f;
  for (int b = 0; b < B_; ++b) {
    const float* p = x + ((size_t)b * C_ + c) * N_;
    for (int n = t * 4; n < N_; n += 1024) {
      float4 v = *(const float4*)(p + n);
      s += (v.x + v.y) + (v.z + v.w);
      s2 += (v.x * v.x + v.y * v.y) + (v.z * v.z + v.w * v.w);
    }
  }
  __shared__ float rs[256], rs2[256];
  rs[t] = s; rs2[t] = s2; __syncthreads();
  for (int off = 128; off > 0; off >>= 1) {
    if (t < off) { rs[t] += rs[t + off]; rs2[t] += rs2[t + off]; }
    __syncthreads();
  }
  if (t == 0) {
    float m = rs[0] * (1.f / 16384.f);
    float v = rs2[0] * (1.f / 16384.f) - m * m;
    mean[c] = m; rstd[c] = rsqrtf(v + 1e-5f);
  }
}

// ---------------- K2: fold BN + split QK scale into weights ----------------
__global__ __launch_bounds__(256) void prep(
    const float* __restrict__ wq, const float* __restrict__ bq,
    const float* __restrict__ wk, const float* __restrict__ bk,
    const float* __restrict__ wv, const float* __restrict__ bv,
    const float* __restrict__ wp,
    const float* __restrict__ gamma, const float* __restrict__ beta,
    const float* __restrict__ mean, const float* __restrict__ rstd,
    unsigned short* __restrict__ wqb, unsigned short* __restrict__ wkb,
    unsigned short* __restrict__ wvb, unsigned short* __restrict__ wpb,
    float* __restrict__ beq, float* __restrict__ bek, float* __restrict__ bev) {
  const float SQ = 0.300280605f;   // sqrt(C^-0.5 * log2(e)); applied to BOTH q and k
  int o = blockIdx.x, c = threadIdx.x;
  float a = gamma[c] * rstd[c];
  float d = beta[c] - mean[c] * a;
  float wqv = wq[o * C_ + c], wkv = wk[o * C_ + c], wvv = wv[o * C_ + c];
  wqb[o * C_ + c] = f2bf(wqv * a * SQ);
  wkb[o * C_ + c] = f2bf(wkv * a * SQ);
  wvb[o * C_ + c] = f2bf(wvv * a);
  wpb[o * C_ + c] = f2bf(wp[o * C_ + c]);
  __shared__ float r0[256], r1[256], r2[256];
  r0[c] = wqv * d; r1[c] = wkv * d; r2[c] = wvv * d; __syncthreads();
  for (int off = 128; off > 0; off >>= 1) {
    if (c < off) { r0[c] += r0[c + off]; r1[c] += r1[c + off]; r2[c] += r2[c + off]; }
    __syncthreads();
  }
  if (c == 0) {
    beq[o] = (bq[o] + r0[0]) * SQ;
    bek[o] = (bk[o] + r1[0]) * SQ;
    bev[o] = bv[o] + r2[0];
  }
}

// ---------------- K3: fused x-convert + QKV GEMM (single-stage LDS); q/k/v FP8 out ----------------
__global__ __launch_bounds__(256) void qkv(
    const float* __restrict__ x,
    const unsigned short* __restrict__ wqb, const unsigned short* __restrict__ wkb,
    const unsigned short* __restrict__ wvb,
    const float* __restrict__ beq, const float* __restrict__ bek,
    const float* __restrict__ bev,
    unsigned char* __restrict__ qB, unsigned char* __restrict__ kB,
    unsigned char* __restrict__ vB) {
  int b = blockIdx.z, oblk = blockIdx.y, n0 = blockIdx.x * 64;
  int tid = threadIdx.x, w = tid >> 6, l = tid & 63, quad = l >> 4, lq = l & 15;
  int orow = oblk * 64 + w * 16 + lq;

  __shared__ unsigned short Ls[64][264];   // 33.8 KB x tile [n][c]

  // ---- stage x -> Ls (ONE barrier) ----
  {
    int cw = tid >> 6, nl = tid & 63;
    const float* xp = x + ((size_t)b * C_ + cw * 64) * N_ + n0 + nl;
#pragma unroll
    for (int i = 0; i < 32; ++i) {
      float f0 = xp[(size_t)(2 * i) * N_];
      float f1 = xp[(size_t)(2 * i + 1) * N_];
      unsigned pk = (unsigned)f2bf(f0) | ((unsigned)f2bf(f1) << 16);
      *(unsigned*)(&Ls[nl][cw * 64 + 2 * i]) = pk;
    }
  }
  __syncthreads();

  f4v aq[4], ak[4], av[4];
#pragma unroll
  for (int nt = 0; nt < 4; ++nt) {
    aq[nt] = (f4v){0.f, 0.f, 0.f, 0.f};
    ak[nt] = (f4v){0.f, 0.f, 0.f, 0.f};
    av[nt] = (f4v){0.f, 0.f, 0.f, 0.f};
  }

#pragma unroll
  for (int kk = 0; kk < 8; ++kk) {
    s8v afq = *(const s8v*)(wqb + (size_t)orow * C_ + kk * 32 + quad * 8);
    s8v afk = *(const s8v*)(wkb + (size_t)orow * C_ + kk * 32 + quad * 8);
    s8v afv = *(const s8v*)(wvb + (size_t)orow * C_ + kk * 32 + quad * 8);
#pragma unroll
    for (int nt = 0; nt < 4; ++nt) {
      s8v bf = *(const s8v*)(&Ls[nt * 16 + lq][kk * 32 + quad * 8]);
      aq[nt] = __builtin_amdgcn_mfma_f32_16x16x32_bf16(afq, bf, aq[nt], 0, 0, 0);
      ak[nt] = __builtin_amdgcn_mfma_f32_16x16x32_bf16(afk, bf, ak[nt], 0, 0, 0);
      av[nt] = __builtin_amdgcn_mfma_f32_16x16x32_bf16(afv, bf, av[nt], 0, 0, 0);
    }
  }

  int obase = oblk * 64;
  unsigned short (*Lr)[72] = (unsigned short(*)[72])Ls;   // repack view (x dead)

  // pass 1: q -> qB ; pass 2: k -> kB   (stage [n][c] bf16; gather 32x32-frag; cvt FP8)
  for (int pass = 0; pass < 2; ++pass) {
    const f4v* acc = (pass == 0) ? aq : ak;
    const float* BE = (pass == 0) ? beq : bek;
    int ob4 = obase + w * 16 + quad * 4;
    float b0 = BE[ob4], b1 = BE[ob4 + 1], b2 = BE[ob4 + 2], b3 = BE[ob4 + 3];
    __syncthreads();
#pragma unroll
    for (int nt = 0; nt < 4; ++nt) {
      unsigned lo = (unsigned)f2bf(acc[nt][0] + b0) | ((unsigned)f2bf(acc[nt][1] + b1) << 16);
      unsigned hi = (unsigned)f2bf(acc[nt][2] + b2) | ((unsigned)f2bf(acc[nt][3] + b3) << 16);
      uint2 pr; pr.x = lo; pr.y = hi;
      *(uint2*)(&Lr[nt * 16 + lq][w * 16 + quad * 4]) = pr;
    }
    __syncthreads();
    {
      unsigned char* dp = (pass == 0) ? qB : kB;
#pragma unroll
      for (int ii = 0; ii < 2; ++ii) {
        int i = tid + ii * 256;
        int g = i >> 8, cs = (i >> 6) & 3, ll = i & 63;
        s8v vv = *(const s8v*)(&Lr[g * 32 + (ll & 31)][cs * 16 + ((ll >> 5) << 3)]);
        unsigned w0 = (unsigned)__builtin_amdgcn_cvt_pk_fp8_f32(
            bf2f((unsigned short)vv[0]), bf2f((unsigned short)vv[1]), 0, false);
        w0 = (unsigned)__builtin_amdgcn_cvt_pk_fp8_f32(
            bf2f((unsigned short)vv[2]), bf2f((unsigned short)vv[3]), (int)w0, true);
        unsigned w1 = (unsigned)__builtin_amdgcn_cvt_pk_fp8_f32(
            bf2f((unsigned short)vv[4]), bf2f((unsigned short)vv[5]), 0, false);
        w1 = (unsigned)__builtin_amdgcn_cvt_pk_fp8_f32(
            bf2f((unsigned short)vv[6]), bf2f((unsigned short)vv[7]), (int)w1, true);
        uint2 pr; pr.x = w0; pr.y = w1;
        size_t dst = ((((size_t)b * 128 + (n0 >> 5) + g) * 16 + (obase >> 4) + cs) * 64 + ll) * 8;
        *(uint2*)(dp + dst) = pr;
      }
    }
  }
  __syncthreads();

  // pass 3: v (stage [c][n] bf16; gather 32x32 A-frag; cvt FP8)
#pragma unroll
  for (int nt = 0; nt < 4; ++nt)
#pragma unroll
    for (int r = 0; r < 4; ++r) {
      int o_ = obase + w * 16 + quad * 4 + r;
      Lr[w * 16 + quad * 4 + r][nt * 16 + lq] = f2bf(av[nt][r] + bev[o_]);
    }
  __syncthreads();
  {
#pragma unroll
    for (int ii = 0; ii < 2; ++ii) {
      int i = tid + ii * 256;
      int g = i >> 8, ks = (i >> 6) & 3, ll = i & 63;
      s8v vv = *(const s8v*)(&Lr[g * 32 + (ll & 31)][ks * 16 + ((ll >> 5) << 3)]);
      unsigned w0 = (unsigned)__builtin_amdgcn_cvt_pk_fp8_f32(
          bf2f((unsigned short)vv[0]), bf2f((unsigned short)vv[1]), 0, false);
      w0 = (unsigned)__builtin_amdgcn_cvt_pk_fp8_f32(
          bf2f((unsigned short)vv[2]), bf2f((unsigned short)vv[3]), (int)w0, true);
      unsigned w1 = (unsigned)__builtin_amdgcn_cvt_pk_fp8_f32(
          bf2f((unsigned short)vv[4]), bf2f((unsigned short)vv[5]), 0, false);
      w1 = (unsigned)__builtin_amdgcn_cvt_pk_fp8_f32(
          bf2f((unsigned short)vv[6]), bf2f((unsigned short)vv[7]), (int)w1, true);
      uint2 pr; pr.x = w0; pr.y = w1;
      size_t dst = ((((size_t)b * 8 + (obase >> 5) + g) * 256 + (n0 >> 4) + ks) * 64 + ll) * 8;
      *(uint2*)(vB + dst) = pr;
    }
  }
}

// ---------------- K4: FMHA — full-FP8 operands: Q resident in regs, no Q LDS ----------------
// r13 attn budget: LDS 4.2k cyc/chunk (32 b128 Q-re-reads dominate) + L2 3.4k,
// serialized at the chunk barrier. fp8 S-phase closes the r6 register gap:
// qf (fp8 B-frags) = 64 VGPR, kf (fp8 A-frags) = 32, vf = 32, S+O = 64 ->
// ~210 live <= 256 at 2 waves/SIMD. Qs tile deleted (no staging, no q-reads);
// main-loop LDS is P-only. K L2 traffic halves. S uses mfma 32x32x16_fp8_fp8
// (= bf16 rate); scale sqrt(QSC) pre-folded into both q and k.
__global__ __launch_bounds__(512, 2) void attn(
    const unsigned char* __restrict__ qB, const unsigned char* __restrict__ kB,
    const unsigned char* __restrict__ vB,
    const unsigned short* __restrict__ wpb, const float* __restrict__ bp,
    const float* __restrict__ x, float* __restrict__ out) {
  int id = blockIdx.x;                       // id&7 = XCD (2 XCDs per batch)
  int b = (id & 7) >> 1;
  int i0 = (((id >> 3) << 1) | (id & 1)) << 6;   // 64 q-rows per block
  int tid = threadIdx.x, w = tid >> 6, l = tid & 63;
  int lh = l >> 5, l31 = l & 31;

  __shared__ unsigned char Ps[2][16384];     // 2 x 16 KB P tiles (fp8)
  __shared__ unsigned short aS[16384];       // 32 KB attn-out tile (bf16, proj input)
  __shared__ float Lw[8][2][32];

  // Q resident in registers: 32 fp8 B-frags (64 VGPR), loaded once from L2.
  i64f qf[2][16];
  {
    const unsigned char* qp = qB + (((size_t)b * 64 + (i0 >> 6)) * 32) * 512 + (size_t)l * 8;
#pragma unroll
    for (int rg = 0; rg < 2; ++rg)
#pragma unroll
      for (int cs = 0; cs < 16; ++cs)
        qf[rg][cs] = *(const i64f*)(qp + (size_t)(rg * 16 + cs) * 512);
  }

  // K (fp8): wave w owns key32-group w of each chunk; advance 8 groups = 65536 B/chunk
  const unsigned char* kp = kB + (((size_t)b * 128 + w) * 16) * 512 + (size_t)l * 8;
  // V (fp8): wave w owns channel-group w; frag ks at +ks*512 B
  const unsigned char* vp = vB + (((size_t)b * 8 + w) * 256) * 512 + (size_t)l * 8;

  // prologue: kf for chunk 0 (fp8: 16 x 8 B = 32 VGPR)
  i64f kf[16];
#pragma unroll
  for (int cs = 0; cs < 16; ++cs) kf[cs] = *(const i64f*)(kp + cs * 512);
  SCHED_FENCE();

  f16v O0 = zf16(), O1 = zf16();   // [rg] channels w*32+chl, rows i0+rg*32+l31
  float ls0 = 0.f, ls1 = 0.f;

  for (int t = 0; t < 16; ++t) {
    // ---- vf prefetch for THIS chunk ----
    i64f vf[16];
#pragma unroll
    for (int ks = 0; ks < 16; ++ks) vf[ks] = *(const i64f*)(vp + ks * 512);
    SCHED_FENCE();
    // ---- S phase: fp8 x fp8, pure-register operands ----
    f16v S0 = zf16(), S1 = zf16();
    __builtin_amdgcn_s_setprio(1);
#pragma unroll
    for (int cs = 0; cs < 16; ++cs) {
      S0 = __builtin_amdgcn_mfma_f32_32x32x16_fp8_fp8(kf[cs], qf[0][cs], S0, 0, 0, 0);
      S1 = __builtin_amdgcn_mfma_f32_32x32x16_fp8_fp8(kf[cs], qf[1][cs], S1, 0, 0, 0);
    }
    __builtin_amdgcn_s_setprio(0);
    SCHED_FENCE();
    // ---- exp2 + fp8 pack + P write. key = w*32 + 8j + 4lh + (0..3), row = rg*32+l31 ----
    unsigned char* Pw = Ps[t & 1] + (w * 4) * 512 + l31 * 8 + lh * 4;
#pragma unroll
    for (int j = 0; j < 4; ++j) {
      float a0 = EXP2(S0[4 * j + 0]), a1 = EXP2(S0[4 * j + 1]);
      float a2 = EXP2(S0[4 * j + 2]), a3 = EXP2(S0[4 * j + 3]);
      ls0 += (a0 + a1) + (a2 + a3);
      unsigned p0 = (unsigned)__builtin_amdgcn_cvt_pk_fp8_f32(a0, a1, 0, false);
      p0 = (unsigned)__builtin_amdgcn_cvt_pk_fp8_f32(a2, a3, (int)p0, true);
      *(unsigned*)(Pw + j * 512) = p0;
      float c0 = EXP2(S1[4 * j + 0]), c1 = EXP2(S1[4 * j + 1]);
      float c2 = EXP2(S1[4 * j + 2]), c3 = EXP2(S1[4 * j + 3]);
      ls1 += (c0 + c1) + (c2 + c3);
      unsigned p1 = (unsigned)__builtin_amdgcn_cvt_pk_fp8_f32(c0, c1, 0, false);
      p1 = (unsigned)__builtin_amdgcn_cvt_pk_fp8_f32(c2, c3, (int)p1, true);
      *(unsigned*)(Pw + j * 512 + 256) = p1;
    }
    __syncthreads();   // P visible; vf landed (issued before S)
    // ---- kf prefetch for NEXT chunk (t=15 read is benign OOB within kB slack) ----
    kp += 65536;
#pragma unroll
    for (int cs = 0; cs < 16; ++cs) kf[cs] = *(const i64f*)(kp + cs * 512);
    SCHED_FENCE();
    // ---- PV phase: fp8 MFMA; this wave's 32 channels, all 256 keys ----
    const unsigned char* Pr = Ps[t & 1] + (size_t)lh * 512 + l31 * 8;
    __builtin_amdgcn_s_setprio(1);
#pragma unroll
    for (int ks = 0; ks < 16; ++ks) {
      i64f p0 = *(const i64f*)(Pr + ks * 1024);
      i64f p1 = *(const i64f*)(Pr + ks * 1024 + 256);
      O0 = __builtin_amdgcn_mfma_f32_32x32x16_fp8_fp8(vf[ks], p0, O0, 0, 0, 0);
      O1 = __builtin_amdgcn_mfma_f32_32x32x16_fp8_fp8(vf[ks], p1, O1, 0, 0, 0);
    }
    __builtin_amdgcn_s_setprio(0);
    vp += 8192;
  }

  // ---- wp A-frag prefetch (registers free now; lands under the reductions) ----
  s8v wf[16];
#pragma unroll
  for (int cs = 0; cs < 16; ++cs)
    wf[cs] = *(const s8v*)(wpb + (size_t)(w * 32 + l31) * 256 + cs * 16 + lh * 8);
  SCHED_FENCE();

  // lsum: lane has sum over its 16 keys/chunk; partner lane (l^32) has the other 16
  ls0 += __shfl_xor(ls0, 32);
  ls1 += __shfl_xor(ls1, 32);
  if (l < 32) { Lw[w][0][l] = ls0; Lw[w][1][l] = ls1; }
  __syncthreads();
  float s0 = 0.f, s1 = 0.f;
#pragma unroll
  for (int ww = 0; ww < 8; ++ww) { s0 += Lw[ww][0][l31]; s1 += Lw[ww][1][l31]; }
  float rl0 = 1.f / s0, rl1 = 1.f / s1;

  // ---- normalize + write attn-out tile to LDS (bf16 16x16 B-frag, tile-local) ----
#pragma unroll
  for (int jj = 0; jj < 4; ++jj) {
    ushort4 pk;
    pk.x = f2bf(O0[4 * jj + 0] * rl0); pk.y = f2bf(O0[4 * jj + 1] * rl0);
    pk.z = f2bf(O0[4 * jj + 2] * rl0); pk.w = f2bf(O0[4 * jj + 3] * rl0);
    int f0 = ((l31 >> 4) * 32 + w * 4 + jj) * 128 + (l31 & 15) * 8 + lh * 4;
    *(ushort4*)(aS + f0) = pk;
    pk.x = f2bf(O1[4 * jj + 0] * rl1); pk.y = f2bf(O1[4 * jj + 1] * rl1);
    pk.z = f2bf(O1[4 * jj + 2] * rl1); pk.w = f2bf(O1[4 * jj + 3] * rl1);
    int f1 = ((2 + (l31 >> 4)) * 32 + w * 4 + jj) * 128 + (l31 & 15) * 8 + lh * 4;
    *(ushort4*)(aS + f1) = pk;
  }
  __syncthreads();   // aS visible

  // ---- projection GEMM: out[o][n] = sum_c wp[o][c] * a[c][n] ----
  f16v OP0 = zf16(), OP1 = zf16();
#pragma unroll
  for (int cs = 0; cs < 16; ++cs) {
    s8v pa0 = *(const s8v*)(aS + ((0 + (l31 >> 4)) * 32 + cs * 2 + lh) * 128 + (l31 & 15) * 8);
    s8v pa1 = *(const s8v*)(aS + ((2 + (l31 >> 4)) * 32 + cs * 2 + lh) * 128 + (l31 & 15) * 8);
    OP0 = __builtin_amdgcn_mfma_f32_32x32x16_bf16(wf[cs], pa0, OP0, 0, 0, 0);
    OP1 = __builtin_amdgcn_mfma_f32_32x32x16_bf16(wf[cs], pa1, OP1, 0, 0, 0);
  }

  // ---- epilogue: out = x + proj + bp ----
#pragma unroll
  for (int r = 0; r < 16; ++r) {
    int o_ = w * 32 + (r & 3) + 8 * (r >> 2) + 4 * lh;
    float bpv = bp[o_];
    size_t ix = ((size_t)b * C_ + o_) * N_ + i0 + l31;
    out[ix]      = x[ix]      + OP0[r] + bpv;
    out[ix + 32] = x[ix + 32] + OP1[r] + bpv;
  }
}

extern "C" void kernel_launch(void* const* d_in, const int* in_sizes, int n_in,
                              void* d_out, int out_size, void* d_ws, size_t ws_size,
                              hipStream_t stream) {
  const float* x     = (const float*)d_in[0];
  const float* gamma = (const float*)d_in[1];
  const float* beta  = (const float*)d_in[2];
  const float* wq    = (const float*)d_in[3];
  const float* bq    = (const float*)d_in[4];
  const float* wk    = (const float*)d_in[5];
  const float* bk    = (const float*)d_in[6];
  const float* wv    = (const float*)d_in[7];
  const float* bv    = (const float*)d_in[8];
  const float* wp    = (const float*)d_in[9];
  const float* bp    = (const float*)d_in[10];
  float* out = (float*)d_out;

  char* ws = (char*)d_ws;
  float* mean = (float*)ws; ws += 1024;
  float* rstd = (float*)ws; ws += 1024;
  float* beq  = (float*)ws; ws += 1024;
  float* bek  = (float*)ws; ws += 1024;
  float* bev  = (float*)ws; ws += 1024;
  unsigned short* wqb = (unsigned short*)ws; ws += C_ * C_ * 2;
  unsigned short* wkb = (unsigned short*)ws; ws += C_ * C_ * 2;
  unsigned short* wvb = (unsigned short*)ws; ws += C_ * C_ * 2;
  unsigned short* wpb = (unsigned short*)ws; ws += C_ * C_ * 2;
  // fp8 q/k/v occupy half their regions; slack absorbs the benign OOB prefetch
  unsigned char* qB = (unsigned char*)ws; ws += (size_t)B_ * N_ * C_ * 2;
  unsigned char* kB = (unsigned char*)ws; ws += (size_t)B_ * N_ * C_ * 2;
  unsigned char* vB = (unsigned char*)ws; ws += (size_t)B_ * N_ * C_ * 2;

  hipLaunchKernelGGL(bn_stats, dim3(C_), dim3(256), 0, stream, x, mean, rstd);
  hipLaunchKernelGGL(prep, dim3(C_), dim3(256), 0, stream,
                     wq, bq, wk, bk, wv, bv, wp, gamma, beta, mean, rstd,
                     wqb, wkb, wvb, wpb, beq, bek, bev);
  hipLaunchKernelGGL(qkv, dim3(N_ / 64, 4, B_), dim3(256), 0, stream,
                     x, wqb, wkb, wvb, beq, bek, bev, qB, kB, vB);
  hipLaunchKernelGGL(attn, dim3(256), dim3(512), 0, stream,
                     qB, kB, vB, wpb, bp, x, out);
}